// Round 7
// baseline (44.669 us; speedup 1.0000x reference)
//
#include <hip/hip_runtime.h>

// Bilinear flow warp, LDS row-tile v4: double-buffered channel pipeline.
// images [32,3,512,512] f32, flows [32,2,512,512] f32 (ch0=dy, ch1=dx).
//
// R6 post-mortem: removing ds_writes (async global_load_lds) gained only
// 0.9us; summed pipe work (~60K cyc/CU) is well under the 105K cycle budget
// -> serialization-bound: each channel = stage -> sync(vmcnt(0) drain =
// full latency stall) -> gather, x3 per block. v4 overlaps: stage(c+1) is
// issued into the OTHER 32KB buffer BEFORE gather(c); the drain at the next
// __syncthreads then finds loads already landed (m201 evidence: ds_reads do
// not auto-wait on outstanding global_load_lds). Hazards: buf[(c+1)&1] was
// last read by gather(c-1), which finished at the sync ending iter c-1 --
// before stage(c+1) issues. LDS 2x32KB=64KB -> 2 blocks/CU (16 waves).

constexpr int C = 3, H = 512, W = 512, HW = H * W;
constexpr int TH = 8, HALO = 4;
constexpr int LROWS = TH + 2 * HALO;      // 16 staged rows
constexpr int LWP   = W;                  // 512: stride == 0 mod 32 banks
constexpr int TILES = 32 * (H / TH);      // 2048 blocks, %8 == 0

__global__ __launch_bounds__(512) void warp_bilinear_rows(
    const float* __restrict__ images,
    const float* __restrict__ flows,
    float* __restrict__ out)
{
    __shared__ float tile[2][LROWS * LWP];   // 2 x 32,768 B

    // XCD-contiguous: XCD r owns tiles [r*256,(r+1)*256) = 4 whole batches.
    int bid = blockIdx.x;
    int tile_id = (bid & 7) * (TILES / 8) + (bid >> 3);
    int b   = tile_id >> 6;               // 64 row-tiles per batch
    int ty0 = (tile_id & 63) * TH;

    int tid = threadIdx.x;                // 0..511 = my column

    // ---- flow load + channel-independent gather state (8 px/thread) ----
    const float* flow_y = flows + (size_t)b * 2 * HW + ty0 * W + tid;
    const float* flow_x = flow_y + HW;

    float dxv[TH], dyv[TH];
    int   li[TH];
    unsigned okm = 0;
#pragma unroll
    for (int k = 0; k < TH; ++k) {
        float fy = flow_y[k * W];
        float fx = flow_x[k * W];
        float sx = fminf(fmaxf((float)tid + fx, 0.0f), (float)(W - 1));
        float sy = fminf(fmaxf((float)(ty0 + k) + fy, 0.0f), (float)(H - 1));
        int x0 = min((int)sx, W - 2);     // sx >= 0 so (int) == floor
        int y0 = min((int)sy, H - 2);
        dxv[k] = sx - (float)x0;
        dyv[k] = sy - (float)y0;
        int ly0 = y0 - (ty0 - HALO);
        bool ok = (ly0 >= 0) & (ly0 <= LROWS - 2);
        okm |= (unsigned)ok << k;
        li[k] = ok ? (ly0 * LWP + x0)     // LDS offset (x needs no halo)
                   : (y0 * W + x0);       // global fallback offset
    }
    bool fast = __all(okm == ((1u << TH) - 1));

    // staging addresses (channel-invariant): wave-uniform row + lane*16B
    int srow[LROWS / 4];
    int scol = (tid & 127) * 4;
#pragma unroll
    for (int it = 0; it < LROWS / 4; ++it) {
        int r = it * 4 + (tid >> 7);
        srow[it] = min(max(ty0 - HALO + r, 0), H - 1);
    }

    auto stage = [&](int c, int buf) {
        const float* gimg = images + ((size_t)b * C + c) * HW;
#pragma unroll
        for (int it = 0; it < LROWS / 4; ++it) {
            int r = it * 4 + (tid >> 7);
            __builtin_amdgcn_global_load_lds(
                (const __attribute__((address_space(1))) void*)(gimg + srow[it] * W + scol),
                (__attribute__((address_space(3))) void*)(&tile[buf][r * LWP + scol]),
                16, 0, 0);
        }
    };

    stage(0, 0);
    __syncthreads();                      // cold drain (only unhidden one)

    for (int c = 0; c < C; ++c) {
        if (c + 1 < C) stage(c + 1, (c + 1) & 1);   // overlap with gather(c)

        const float* gimg = images + ((size_t)b * C + c) * HW;  // fallback
        const float* tb = tile[c & 1];
        float* outc = out + ((size_t)b * C + c) * HW + ty0 * W + tid;

        if (fast) {
#pragma unroll
            for (int k = 0; k < TH; ++k) {
                float dx = dxv[k], dy = dyv[k];
                float wa = (1.0f - dx) * (1.0f - dy);
                float wb = (1.0f - dx) * dy;
                float wc = dx * (1.0f - dy);
                float wd = dx * dy;
                int t = li[k];
                float Ia = tb[t];        float Ic = tb[t + 1];
                float Ib = tb[t + LWP];  float Id = tb[t + LWP + 1];
                __builtin_nontemporal_store(
                    wa * Ia + wb * Ib + wc * Ic + wd * Id, outc + k * W);
            }
        } else {                           // rare: |dy| > ~4 near strip edge
#pragma unroll
            for (int k = 0; k < TH; ++k) {
                float dx = dxv[k], dy = dyv[k];
                float wa = (1.0f - dx) * (1.0f - dy);
                float wb = (1.0f - dx) * dy;
                float wc = dx * (1.0f - dy);
                float wd = dx * dy;
                float Ia, Ib, Ic, Id;
                if ((okm >> k) & 1) {
                    int t = li[k];
                    Ia = tb[t];        Ic = tb[t + 1];
                    Ib = tb[t + LWP];  Id = tb[t + LWP + 1];
                } else {
                    int g = li[k];
                    Ia = gimg[g];        Ic = gimg[g + 1];
                    Ib = gimg[g + W];    Id = gimg[g + W + 1];
                }
                __builtin_nontemporal_store(
                    wa * Ia + wb * Ib + wc * Ic + wd * Id, outc + k * W);
            }
        }
        __syncthreads();   // gather(c) done; drains stage(c+1) (already landed)
    }
}

extern "C" void kernel_launch(void* const* d_in, const int* in_sizes, int n_in,
                              void* d_out, int out_size, void* d_ws, size_t ws_size,
                              hipStream_t stream) {
    const float* images = (const float*)d_in[0];
    const float* flows  = (const float*)d_in[1];
    float* out = (float*)d_out;

    dim3 block(512);
    dim3 grid(TILES);                     // 2048 blocks
    hipLaunchKernelGGL(warp_bilinear_rows, grid, block, 0, stream,
                       images, flows, out);
}